// Round 11
// baseline (24.500 us; speedup 1.0000x reference)
//
#include <hip/hip_runtime.h>
#include <math.h>

#define NTH 256

__device__ __forceinline__ float frcp(float x) { return __builtin_amdgcn_rcpf(x); }
// reciprocal with sign-preserving epsilon: bounded result on degenerate edges
// (mirrors the reference's +EPS denominator role). Note frcp_eps(-d) == -frcp_eps(d).
__device__ __forceinline__ float frcp_eps(float d) {
    float es = __int_as_float((__float_as_int(d) & 0x80000000) | 0x322BCC77); // copysign(1e-8f,d)
    return __builtin_amdgcn_rcpf(d + es);
}

// R10 compute (Green's-theorem closed-form box-clip area) + barrier-free
// per-wave LDS staging: each wave coalesces its OWN 64 boxes (float4 loads,
// ~56 line-transactions/wave vs ~280 scattered), writes its private LDS
// region, reads back at dword-stride 7 (gcd(7,32)=1 -> inherent 2-way only).
// NO __syncthreads in the staging path: DS ops are in-order per wave, so the
// write->read hazard is wave-private and waves stay staggered (R8's regression
// was the block-wide barrier killing wave-level overlap, not staging itself).

__global__ __launch_bounds__(NTH, 8) void giou_kernel(
    const float* __restrict__ box, const float* __restrict__ tbox,
    double* __restrict__ wsum, int N)
{
    __shared__ float lsf[4 * 896];       // 4 waves x (448 box + 448 tbox) dwords
    __shared__ double red[4];
    const int tid = threadIdx.x;
    const int w = tid >> 6, l = tid & 63;
    const int gid = blockIdx.x * NTH + tid;

    // ---- per-wave coalesced staging (no barrier) ----
    float* reg = lsf + w * 896;
    {
        const float4* g1 = (const float4*)box;
        const float4* g2 = (const float4*)tbox;
        float4* r4a = (float4*)reg;          // this wave's box region: 112 float4
        float4* r4b = (float4*)(reg + 448);  // this wave's tbox region
        int base4 = blockIdx.x * 448 + w * 112;  // 64 boxes * 7 floats = 112 float4
        int tot4 = (N * 7) >> 2;                 // N*7 divisible by 4 (7M)
        int i0 = base4 + l;
        if (i0 < tot4) { r4a[l] = g1[i0]; r4b[l] = g2[i0]; }
        int i1 = base4 + 64 + l;
        if (l < 48 && i1 < tot4) { r4a[64 + l] = g1[i1]; r4b[64 + l] = g2[i1]; }
    }

    float loss = 0.0f;
    if (gid < N) {
        // wave-private LDS readback (in-order DS guarantees write->read)
        const float* m1 = reg + 7 * l;
        const float* m2 = reg + 448 + 7 * l;
        float cx1 = m1[0], cy1 = m1[1];
        float w1 = __expf(m1[3]), l1 = __expf(m1[4]);
        float yaw1 = m1[6];
        float cx2 = m2[0], cy2 = m2[1];
        float w2 = __expf(m2[3]), l2 = __expf(m2[4]);
        float yaw2 = m2[6];

        float s1 = __sinf(yaw1), c1 = __cosf(yaw1);
        float s2 = __sinf(yaw2), c2 = __cosf(yaw2);
        float hx1 = 0.5f * w1, hy1 = 0.5f * l1;
        float hx  = 0.5f * w2, hy  = 0.5f * l2;   // box2 half-extents (clip box)

        // world-frame enclosing bbox via exact extent identity |u|+|v|
        float e1x = fmaf(hx1, fabsf(c1), hy1 * fabsf(s1));
        float e1y = fmaf(hx1, fabsf(s1), hy1 * fabsf(c1));
        float e2x = fmaf(hx, fabsf(c2), hy * fabsf(s2));
        float e2y = fmaf(hx, fabsf(s2), hy * fabsf(c2));
        float enc;
        {
            float xmin = fminf(cx1 - e1x, cx2 - e2x);
            float xmax = fmaxf(cx1 + e1x, cx2 + e2x);
            float ymin = fminf(cy1 - e1y, cy2 - e2y);
            float ymax = fmaxf(cy1 + e1y, cy2 + e2y);
            enc = (xmax - xmin) * (ymax - ymin);
        }

        // ---- transform quad1 into box2's frame (box2 -> axis-aligned) ----
        float sr = s1 * c2 - c1 * s2;       // sin(yaw1-yaw2)
        float cr = c1 * c2 + s1 * s2;       // cos(yaw1-yaw2)
        float tx = cx1 - cx2, ty = cy1 - cy2;
        float dxc =  c2 * tx + s2 * ty;     // R(-yaw2)*(c1-c2)
        float dyc = -s2 * tx + c2 * ty;
        float ux = hx1 * cr, uy = hx1 * sr;
        float vx = -hy1 * sr, vy = hy1 * cr;

        // CCW corners: d-u-v, d+u-v, d+u+v, d-u+v
        float qx[4], qy[4];
        qx[0] = dxc - ux - vx;  qy[0] = dyc - uy - vy;
        qx[1] = dxc + ux - vx;  qy[1] = dyc + uy - vy;
        qx[2] = dxc + ux + vx;  qy[2] = dyc + uy + vy;
        qx[3] = dxc - ux + vx;  qy[3] = dyc - uy + vy;

        // edge vectors (exact): e0=+2u e1=+2v e2=-2u e3=-2v; 4 shared rcps
        float Ux = 2.0f * ux, Uy = 2.0f * uy;
        float Vx = 2.0f * vx, Vy = 2.0f * vy;
        float rUx = frcp_eps(Ux), rUy = frcp_eps(Uy);
        float rVx = frcp_eps(Vx), rVy = frcp_eps(Vy);

        // hoisted per-vertex threshold compares (shared by adjacent edges)
        bool gT[4], gB[4];
#pragma unroll
        for (int k = 0; k < 4; ++k) { gT[k] = qy[k] > hy; gB[k] = qy[k] > -hy; }

        const float INFP = __int_as_float(0x7f800000);
        float areaP = 0.0f;
        float xTmin = INFP, xTmax = -INFP;   // crossings with y=+hy
        float xBmin = INFP, xBmax = -INFP;   // crossings with y=-hy
#pragma unroll
        for (int i = 0; i < 4; ++i) {
            float px = qx[i], py = qy[i];
            int ip1 = (i + 1) & 3;
            // edge direction and shared reciprocals (negation = input modifier)
            float dxe = (i == 0) ? Ux : (i == 1) ? Vx : (i == 2) ? -Ux : -Vx;
            float dye = (i == 0) ? Uy : (i == 1) ? Vy : (i == 2) ? -Uy : -Vy;
            float rdx = (i == 0) ? rUx : (i == 1) ? rVx : (i == 2) ? -rUx : -rVx;
            float rdy = (i == 0) ? rUy : (i == 1) ? rVy : (i == 2) ? -rUy : -rVy;

            // parameter interval of this edge inside the box
            float ta = (-hx - px) * rdx, tb = (hx - px) * rdx;
            float txlo = fminf(ta, tb), txhi = fmaxf(ta, tb);
            float tc = (-hy - py) * rdy, td = (hy - py) * rdy;
            float tylo = fminf(tc, td), tyhi = fmaxf(tc, td);
            float t0 = fmaxf(fmaxf(txlo, tylo), 0.0f);
            float t1 = fminf(fminf(txhi, tyhi), 1.0f);
            float dt = fmaxf(t1 - t0, 0.0f);
            // -∫ y dx over [t0,t1]
            areaP -= dxe * dt * fmaf(0.5f * dye, t0 + t1, py);

            // crossings with the horizontal box lines (correction terms)
            bool crT = gT[i] != gT[ip1];
            float xT = fmaf(td, dxe, px);            // td == (hy-py)*rdy
            xTmin = fminf(xTmin, crT ? xT : INFP);
            xTmax = fmaxf(xTmax, crT ? xT : -INFP);
            bool crB = gB[i] != gB[ip1];
            float xB = fmaf(tc, dxe, px);            // tc == (-hy-py)*rdy
            xBmin = fminf(xBmin, crB ? xB : INFP);
            xBmax = fmaxf(xBmax, crB ? xB : -INFP);
        }
        // empty-crossing case: -INF - INF = -INF -> max(0,.) = 0 (no guards)
        float Ltop = fmaxf(0.0f, fminf(xTmax, hx) - fmaxf(xTmin, -hx));
        float Lbot = fmaxf(0.0f, fminf(xBmax, hx) - fmaxf(xBmin, -hx));
        float inter = fabsf(fmaf(hy, Ltop + Lbot, areaP));

        // ---- giou (areas rotation-invariant; bbox in world frame) ----
        float area1 = w1 * l1, area2 = w2 * l2;
        float uni = area1 + area2 - inter;
        float giou = inter * frcp(uni + 1e-8f) - (enc - uni) * frcp(enc + 1e-8f);
        loss = 1.0f - giou;
    }

    // ---- reduction: f32 wave shuffle -> f64 block partial -> per-block store ----
    float wsf = loss;
#pragma unroll
    for (int o = 32; o > 0; o >>= 1) wsf += __shfl_down(wsf, o, 64);

    if ((tid & 63) == 0) red[tid >> 6] = (double)wsf;
    __syncthreads();
    if (tid == 0)
        wsum[blockIdx.x] = red[0] + red[1] + red[2] + red[3];  // no memset, no atomic
}

__global__ __launch_bounds__(NTH) void finalize_kernel(
    const double* __restrict__ ws, int nblk,
    const int* __restrict__ avgp, float* __restrict__ out)
{
    __shared__ double r[NTH];
    int t = threadIdx.x;
    double v = 0.0;
    for (int i = t; i < nblk; i += NTH) v += ws[i];
    r[t] = v;
    __syncthreads();
#pragma unroll
    for (int s = NTH / 2; s > 0; s >>= 1) {
        if (t < s) r[t] += r[t + s];
        __syncthreads();
    }
    if (t == 0) {
        int ib = *avgp;
        float fb = __int_as_float(ib);
        float av;
        if (ib > 0 && fabsf(fb) < 1e-20f) av = (float)ib;   // int32 payload
        else av = fb;                                        // f32 payload fallback
        if (!(av >= 1.0f)) av = 1.0f;
        out[0] = (float)(r[0] / (double)av);
    }
}

extern "C" void kernel_launch(void* const* d_in, const int* in_sizes, int n_in,
                              void* d_out, int out_size, void* d_ws, size_t ws_size,
                              hipStream_t stream) {
    const float* box  = (const float*)d_in[0];
    const float* tbox = (const float*)d_in[1];
    const int*   avgp = (const int*)d_in[2];
    int N = in_sizes[0] / 7;
    double* ws = (double*)d_ws;

    int blocks = (N + NTH - 1) / NTH;
    giou_kernel<<<blocks, NTH, 0, stream>>>(box, tbox, ws, N);
    finalize_kernel<<<1, NTH, 0, stream>>>(ws, blocks, avgp, (float*)d_out);
}

// Round 12
// 19.708 us; speedup vs baseline: 1.2432x; 1.2432x over previous
//
#include <hip/hip_runtime.h>
#include <math.h>

#define NTH 256

__device__ __forceinline__ float frcp(float x) { return __builtin_amdgcn_rcpf(x); }
// reciprocal with sign-preserving epsilon: bounded result on degenerate edges
// (mirrors the reference's +EPS denominator role). Note frcp_eps(-d) == -frcp_eps(d).
__device__ __forceinline__ float frcp_eps(float d) {
    float es = __int_as_float((__float_as_int(d) & 0x80000000) | 0x322BCC77); // copysign(1e-8f,d)
    return __builtin_amdgcn_rcpf(d + es);
}

// R10 compute (Green's-theorem closed-form box-clip area; direct scattered
// loads — both LDS staging variants measured slower: R8 +2us, R11 +3.4us),
// now ILP-2: each thread runs TWO independent box pairs. Occupancy halves
// (~5 waves/SIMD) which R6/R7 proved costless; dependency-latency stalls are
// the binding constraint and two interleaved chains fill the issue slots.

__device__ __forceinline__ float giou_loss_one(const float* __restrict__ b1,
                                               const float* __restrict__ b2)
{
    float cx1 = b1[0], cy1 = b1[1];
    float w1 = __expf(b1[3]), l1 = __expf(b1[4]);
    float yaw1 = b1[6];
    float cx2 = b2[0], cy2 = b2[1];
    float w2 = __expf(b2[3]), l2 = __expf(b2[4]);
    float yaw2 = b2[6];

    float s1 = __sinf(yaw1), c1 = __cosf(yaw1);
    float s2 = __sinf(yaw2), c2 = __cosf(yaw2);
    float hx1 = 0.5f * w1, hy1 = 0.5f * l1;
    float hx  = 0.5f * w2, hy  = 0.5f * l2;   // box2 half-extents (clip box)

    // world-frame enclosing bbox via exact extent identity |u|+|v|
    float e1x = fmaf(hx1, fabsf(c1), hy1 * fabsf(s1));
    float e1y = fmaf(hx1, fabsf(s1), hy1 * fabsf(c1));
    float e2x = fmaf(hx, fabsf(c2), hy * fabsf(s2));
    float e2y = fmaf(hx, fabsf(s2), hy * fabsf(c2));
    float enc;
    {
        float xmin = fminf(cx1 - e1x, cx2 - e2x);
        float xmax = fmaxf(cx1 + e1x, cx2 + e2x);
        float ymin = fminf(cy1 - e1y, cy2 - e2y);
        float ymax = fmaxf(cy1 + e1y, cy2 + e2y);
        enc = (xmax - xmin) * (ymax - ymin);
    }

    // ---- transform quad1 into box2's frame (box2 -> axis-aligned) ----
    float sr = s1 * c2 - c1 * s2;       // sin(yaw1-yaw2)
    float cr = c1 * c2 + s1 * s2;       // cos(yaw1-yaw2)
    float tx = cx1 - cx2, ty = cy1 - cy2;
    float dxc =  c2 * tx + s2 * ty;     // R(-yaw2)*(c1-c2)
    float dyc = -s2 * tx + c2 * ty;
    float ux = hx1 * cr, uy = hx1 * sr;
    float vx = -hy1 * sr, vy = hy1 * cr;

    // CCW corners: d-u-v, d+u-v, d+u+v, d-u+v
    float qx[4], qy[4];
    qx[0] = dxc - ux - vx;  qy[0] = dyc - uy - vy;
    qx[1] = dxc + ux - vx;  qy[1] = dyc + uy - vy;
    qx[2] = dxc + ux + vx;  qy[2] = dyc + uy + vy;
    qx[3] = dxc - ux + vx;  qy[3] = dyc - uy + vy;

    // edge vectors (exact): e0=+2u e1=+2v e2=-2u e3=-2v; 4 shared rcps
    float Ux = 2.0f * ux, Uy = 2.0f * uy;
    float Vx = 2.0f * vx, Vy = 2.0f * vy;
    float rUx = frcp_eps(Ux), rUy = frcp_eps(Uy);
    float rVx = frcp_eps(Vx), rVy = frcp_eps(Vy);

    // hoisted per-vertex threshold compares (shared by adjacent edges)
    bool gT[4], gB[4];
#pragma unroll
    for (int k = 0; k < 4; ++k) { gT[k] = qy[k] > hy; gB[k] = qy[k] > -hy; }

    const float INFP = __int_as_float(0x7f800000);
    float areaP = 0.0f;
    float xTmin = INFP, xTmax = -INFP;   // crossings with y=+hy
    float xBmin = INFP, xBmax = -INFP;   // crossings with y=-hy
#pragma unroll
    for (int i = 0; i < 4; ++i) {
        float px = qx[i], py = qy[i];
        int ip1 = (i + 1) & 3;
        // edge direction and shared reciprocals (negation = input modifier)
        float dxe = (i == 0) ? Ux : (i == 1) ? Vx : (i == 2) ? -Ux : -Vx;
        float dye = (i == 0) ? Uy : (i == 1) ? Vy : (i == 2) ? -Uy : -Vy;
        float rdx = (i == 0) ? rUx : (i == 1) ? rVx : (i == 2) ? -rUx : -rVx;
        float rdy = (i == 0) ? rUy : (i == 1) ? rVy : (i == 2) ? -rUy : -rVy;

        // parameter interval of this edge inside the box
        float ta = (-hx - px) * rdx, tb = (hx - px) * rdx;
        float txlo = fminf(ta, tb), txhi = fmaxf(ta, tb);
        float tc = (-hy - py) * rdy, td = (hy - py) * rdy;
        float tylo = fminf(tc, td), tyhi = fmaxf(tc, td);
        float t0 = fmaxf(fmaxf(txlo, tylo), 0.0f);
        float t1 = fminf(fminf(txhi, tyhi), 1.0f);
        float dt = fmaxf(t1 - t0, 0.0f);
        // -∫ y dx over [t0,t1]
        areaP -= dxe * dt * fmaf(0.5f * dye, t0 + t1, py);

        // crossings with the horizontal box lines (correction terms)
        bool crT = gT[i] != gT[ip1];
        float xT = fmaf(td, dxe, px);            // td == (hy-py)*rdy
        xTmin = fminf(xTmin, crT ? xT : INFP);
        xTmax = fmaxf(xTmax, crT ? xT : -INFP);
        bool crB = gB[i] != gB[ip1];
        float xB = fmaf(tc, dxe, px);            // tc == (-hy-py)*rdy
        xBmin = fminf(xBmin, crB ? xB : INFP);
        xBmax = fmaxf(xBmax, crB ? xB : -INFP);
    }
    // empty-crossing case: -INF - INF = -INF -> max(0,.) = 0 (no guards)
    float Ltop = fmaxf(0.0f, fminf(xTmax, hx) - fmaxf(xTmin, -hx));
    float Lbot = fmaxf(0.0f, fminf(xBmax, hx) - fmaxf(xBmin, -hx));
    float inter = fabsf(fmaf(hy, Ltop + Lbot, areaP));

    // ---- giou (areas rotation-invariant; bbox in world frame) ----
    float area1 = w1 * l1, area2 = w2 * l2;
    float uni = area1 + area2 - inter;
    float giou = inter * frcp(uni + 1e-8f) - (enc - uni) * frcp(enc + 1e-8f);
    return 1.0f - giou;
}

__global__ __launch_bounds__(NTH) void giou_kernel(
    const float* __restrict__ box, const float* __restrict__ tbox,
    double* __restrict__ wsum, int N)
{
    __shared__ double red[4];
    const int tid = threadIdx.x;
    const int g0 = blockIdx.x * (2 * NTH) + tid;
    const int g1 = g0 + NTH;

    // branchless tail: clamp index, select-to-zero -> one straight-line block,
    // scheduler free to interleave the two independent chains
    int c0 = g0 < N ? g0 : N - 1;
    int c1 = g1 < N ? g1 : N - 1;
    float l0 = giou_loss_one(box + (size_t)c0 * 7, tbox + (size_t)c0 * 7);
    float l1 = giou_loss_one(box + (size_t)c1 * 7, tbox + (size_t)c1 * 7);
    float loss = (g0 < N ? l0 : 0.0f) + (g1 < N ? l1 : 0.0f);

    // ---- reduction: f32 wave shuffle -> f64 block partial -> per-block store ----
#pragma unroll
    for (int o = 32; o > 0; o >>= 1) loss += __shfl_down(loss, o, 64);

    if ((tid & 63) == 0) red[tid >> 6] = (double)loss;
    __syncthreads();
    if (tid == 0)
        wsum[blockIdx.x] = red[0] + red[1] + red[2] + red[3];  // no memset, no atomic
}

__global__ __launch_bounds__(NTH) void finalize_kernel(
    const double* __restrict__ ws, int nblk,
    const int* __restrict__ avgp, float* __restrict__ out)
{
    __shared__ double r[NTH];
    int t = threadIdx.x;
    double v = 0.0;
    for (int i = t; i < nblk; i += NTH) v += ws[i];
    r[t] = v;
    __syncthreads();
#pragma unroll
    for (int s = NTH / 2; s > 0; s >>= 1) {
        if (t < s) r[t] += r[t + s];
        __syncthreads();
    }
    if (t == 0) {
        int ib = *avgp;
        float fb = __int_as_float(ib);
        float av;
        if (ib > 0 && fabsf(fb) < 1e-20f) av = (float)ib;   // int32 payload
        else av = fb;                                        // f32 payload fallback
        if (!(av >= 1.0f)) av = 1.0f;
        out[0] = (float)(r[0] / (double)av);
    }
}

extern "C" void kernel_launch(void* const* d_in, const int* in_sizes, int n_in,
                              void* d_out, int out_size, void* d_ws, size_t ws_size,
                              hipStream_t stream) {
    const float* box  = (const float*)d_in[0];
    const float* tbox = (const float*)d_in[1];
    const int*   avgp = (const int*)d_in[2];
    int N = in_sizes[0] / 7;
    double* ws = (double*)d_ws;

    int blocks = (N + 2 * NTH - 1) / (2 * NTH);
    giou_kernel<<<blocks, NTH, 0, stream>>>(box, tbox, ws, N);
    finalize_kernel<<<1, NTH, 0, stream>>>(ws, blocks, avgp, (float*)d_out);
}

// Round 13
// 19.493 us; speedup vs baseline: 1.2569x; 1.0110x over previous
//
#include <hip/hip_runtime.h>
#include <math.h>

#define NTH 256

__device__ __forceinline__ float frcp(float x) { return __builtin_amdgcn_rcpf(x); }
// reciprocal with sign-preserving epsilon: bounded result on degenerate edges
// (mirrors the reference's +EPS denominator role). Note frcp_eps(-d) == -frcp_eps(d).
__device__ __forceinline__ float frcp_eps(float d) {
    float es = __int_as_float((__float_as_int(d) & 0x80000000) | 0x322BCC77); // copysign(1e-8f,d)
    return __builtin_amdgcn_rcpf(d + es);
}

// 4-byte-aligned float4: boxes start at 28B offsets (4B aligned only), so the
// vector loads must not assume 16B alignment. Two overlapping 16B loads cover
// fields 0..3 and 3..6 -> 2 VMEM instrs per box-array instead of 5 scalar
// loads (wave line-transactions 560 -> 224; TA occupancy was the largest
// remaining term in the cycle model).
typedef float float4a __attribute__((ext_vector_type(4), aligned(4)));

__device__ __forceinline__ void load_box(const float* __restrict__ p,
                                         float& cx, float& cy,
                                         float& lw, float& ll, float& yaw) {
    float4a a = *reinterpret_cast<const float4a*>(p);      // fields 0,1,2,3
    float4a b = *reinterpret_cast<const float4a*>(p + 3);  // fields 3,4,5,6
    cx = a.x; cy = a.y; lw = a.w; ll = b.y; yaw = b.w;
}

// Green's-theorem closed-form box-clip area (R9/R10), ILP-2 (R12).

__device__ __forceinline__ float giou_loss_one(const float* __restrict__ b1,
                                               const float* __restrict__ b2)
{
    float cx1, cy1, lw1, ll1, yaw1;
    float cx2, cy2, lw2, ll2, yaw2;
    load_box(b1, cx1, cy1, lw1, ll1, yaw1);
    load_box(b2, cx2, cy2, lw2, ll2, yaw2);
    float w1 = __expf(lw1), l1 = __expf(ll1);
    float w2 = __expf(lw2), l2 = __expf(ll2);

    float s1 = __sinf(yaw1), c1 = __cosf(yaw1);
    float s2 = __sinf(yaw2), c2 = __cosf(yaw2);
    float hx1 = 0.5f * w1, hy1 = 0.5f * l1;
    float hx  = 0.5f * w2, hy  = 0.5f * l2;   // box2 half-extents (clip box)

    // world-frame enclosing bbox via exact extent identity |u|+|v|
    float e1x = fmaf(hx1, fabsf(c1), hy1 * fabsf(s1));
    float e1y = fmaf(hx1, fabsf(s1), hy1 * fabsf(c1));
    float e2x = fmaf(hx, fabsf(c2), hy * fabsf(s2));
    float e2y = fmaf(hx, fabsf(s2), hy * fabsf(c2));
    float enc;
    {
        float xmin = fminf(cx1 - e1x, cx2 - e2x);
        float xmax = fmaxf(cx1 + e1x, cx2 + e2x);
        float ymin = fminf(cy1 - e1y, cy2 - e2y);
        float ymax = fmaxf(cy1 + e1y, cy2 + e2y);
        enc = (xmax - xmin) * (ymax - ymin);
    }

    // ---- transform quad1 into box2's frame (box2 -> axis-aligned) ----
    float sr = s1 * c2 - c1 * s2;       // sin(yaw1-yaw2)
    float cr = c1 * c2 + s1 * s2;       // cos(yaw1-yaw2)
    float tx = cx1 - cx2, ty = cy1 - cy2;
    float dxc =  c2 * tx + s2 * ty;     // R(-yaw2)*(c1-c2)
    float dyc = -s2 * tx + c2 * ty;
    float ux = hx1 * cr, uy = hx1 * sr;
    float vx = -hy1 * sr, vy = hy1 * cr;

    // CCW corners: d-u-v, d+u-v, d+u+v, d-u+v
    float qx[4], qy[4];
    qx[0] = dxc - ux - vx;  qy[0] = dyc - uy - vy;
    qx[1] = dxc + ux - vx;  qy[1] = dyc + uy - vy;
    qx[2] = dxc + ux + vx;  qy[2] = dyc + uy + vy;
    qx[3] = dxc - ux + vx;  qy[3] = dyc - uy + vy;

    // edge vectors (exact): e0=+2u e1=+2v e2=-2u e3=-2v; 4 shared rcps
    float Ux = 2.0f * ux, Uy = 2.0f * uy;
    float Vx = 2.0f * vx, Vy = 2.0f * vy;
    float rUx = frcp_eps(Ux), rUy = frcp_eps(Uy);
    float rVx = frcp_eps(Vx), rVy = frcp_eps(Vy);

    // hoisted per-vertex threshold compares (shared by adjacent edges)
    bool gT[4], gB[4];
#pragma unroll
    for (int k = 0; k < 4; ++k) { gT[k] = qy[k] > hy; gB[k] = qy[k] > -hy; }

    const float INFP = __int_as_float(0x7f800000);
    float areaP = 0.0f;
    float xTmin = INFP, xTmax = -INFP;   // crossings with y=+hy
    float xBmin = INFP, xBmax = -INFP;   // crossings with y=-hy
#pragma unroll
    for (int i = 0; i < 4; ++i) {
        float px = qx[i], py = qy[i];
        int ip1 = (i + 1) & 3;
        // edge direction and shared reciprocals (negation = input modifier)
        float dxe = (i == 0) ? Ux : (i == 1) ? Vx : (i == 2) ? -Ux : -Vx;
        float dye = (i == 0) ? Uy : (i == 1) ? Vy : (i == 2) ? -Uy : -Vy;
        float rdx = (i == 0) ? rUx : (i == 1) ? rVx : (i == 2) ? -rUx : -rVx;
        float rdy = (i == 0) ? rUy : (i == 1) ? rVy : (i == 2) ? -rUy : -rVy;

        // parameter interval of this edge inside the box
        float ta = (-hx - px) * rdx, tb = (hx - px) * rdx;
        float txlo = fminf(ta, tb), txhi = fmaxf(ta, tb);
        float tc = (-hy - py) * rdy, td = (hy - py) * rdy;
        float tylo = fminf(tc, td), tyhi = fmaxf(tc, td);
        float t0 = fmaxf(fmaxf(txlo, tylo), 0.0f);
        float t1 = fminf(fminf(txhi, tyhi), 1.0f);
        float dt = fmaxf(t1 - t0, 0.0f);
        // -∫ y dx over [t0,t1]
        areaP -= dxe * dt * fmaf(0.5f * dye, t0 + t1, py);

        // crossings with the horizontal box lines (correction terms)
        bool crT = gT[i] != gT[ip1];
        float xT = fmaf(td, dxe, px);            // td == (hy-py)*rdy
        xTmin = fminf(xTmin, crT ? xT : INFP);
        xTmax = fmaxf(xTmax, crT ? xT : -INFP);
        bool crB = gB[i] != gB[ip1];
        float xB = fmaf(tc, dxe, px);            // tc == (-hy-py)*rdy
        xBmin = fminf(xBmin, crB ? xB : INFP);
        xBmax = fmaxf(xBmax, crB ? xB : -INFP);
    }
    // empty-crossing case: -INF - INF = -INF -> max(0,.) = 0 (no guards)
    float Ltop = fmaxf(0.0f, fminf(xTmax, hx) - fmaxf(xTmin, -hx));
    float Lbot = fmaxf(0.0f, fminf(xBmax, hx) - fmaxf(xBmin, -hx));
    float inter = fabsf(fmaf(hy, Ltop + Lbot, areaP));

    // ---- giou (areas rotation-invariant; bbox in world frame) ----
    float area1 = w1 * l1, area2 = w2 * l2;
    float uni = area1 + area2 - inter;
    float giou = inter * frcp(uni + 1e-8f) - (enc - uni) * frcp(enc + 1e-8f);
    return 1.0f - giou;
}

__global__ __launch_bounds__(NTH) void giou_kernel(
    const float* __restrict__ box, const float* __restrict__ tbox,
    double* __restrict__ wsum, int N)
{
    __shared__ double red[4];
    const int tid = threadIdx.x;
    const int g0 = blockIdx.x * (2 * NTH) + tid;
    const int g1 = g0 + NTH;

    // branchless tail: clamp index, select-to-zero -> one straight-line block,
    // scheduler free to interleave the two independent chains
    int c0 = g0 < N ? g0 : N - 1;
    int c1 = g1 < N ? g1 : N - 1;
    float l0 = giou_loss_one(box + (size_t)c0 * 7, tbox + (size_t)c0 * 7);
    float l1 = giou_loss_one(box + (size_t)c1 * 7, tbox + (size_t)c1 * 7);
    float loss = (g0 < N ? l0 : 0.0f) + (g1 < N ? l1 : 0.0f);

    // ---- reduction: f32 wave shuffle -> f64 block partial -> per-block store ----
#pragma unroll
    for (int o = 32; o > 0; o >>= 1) loss += __shfl_down(loss, o, 64);

    if ((tid & 63) == 0) red[tid >> 6] = (double)loss;
    __syncthreads();
    if (tid == 0)
        wsum[blockIdx.x] = red[0] + red[1] + red[2] + red[3];  // no memset, no atomic
}

__global__ __launch_bounds__(NTH) void finalize_kernel(
    const double* __restrict__ ws, int nblk,
    const int* __restrict__ avgp, float* __restrict__ out)
{
    __shared__ double r[NTH];
    int t = threadIdx.x;
    double v = 0.0;
    for (int i = t; i < nblk; i += NTH) v += ws[i];
    r[t] = v;
    __syncthreads();
#pragma unroll
    for (int s = NTH / 2; s > 0; s >>= 1) {
        if (t < s) r[t] += r[t + s];
        __syncthreads();
    }
    if (t == 0) {
        int ib = *avgp;
        float fb = __int_as_float(ib);
        float av;
        if (ib > 0 && fabsf(fb) < 1e-20f) av = (float)ib;   // int32 payload
        else av = fb;                                        // f32 payload fallback
        if (!(av >= 1.0f)) av = 1.0f;
        out[0] = (float)(r[0] / (double)av);
    }
}

extern "C" void kernel_launch(void* const* d_in, const int* in_sizes, int n_in,
                              void* d_out, int out_size, void* d_ws, size_t ws_size,
                              hipStream_t stream) {
    const float* box  = (const float*)d_in[0];
    const float* tbox = (const float*)d_in[1];
    const int*   avgp = (const int*)d_in[2];
    int N = in_sizes[0] / 7;
    double* ws = (double*)d_ws;

    int blocks = (N + 2 * NTH - 1) / (2 * NTH);
    giou_kernel<<<blocks, NTH, 0, stream>>>(box, tbox, ws, N);
    finalize_kernel<<<1, NTH, 0, stream>>>(ws, blocks, avgp, (float*)d_out);
}

// Round 14
// 18.930 us; speedup vs baseline: 1.2943x; 1.0298x over previous
//
#include <hip/hip_runtime.h>
#include <math.h>

#define NTH 256

__device__ __forceinline__ float frcp(float x) { return __builtin_amdgcn_rcpf(x); }
// reciprocal with sign-preserving epsilon: bounded result on degenerate edges
// (mirrors the reference's +EPS denominator role). Note frcp_eps(-d) == -frcp_eps(d).
__device__ __forceinline__ float frcp_eps(float d) {
    float es = __int_as_float((__float_as_int(d) & 0x80000000) | 0x322BCC77); // copysign(1e-8f,d)
    return __builtin_amdgcn_rcpf(d + es);
}

// 4-byte-aligned float4 loads (boxes start at 28B offsets): two overlapping
// 16B loads cover fields 0..3 and 3..6.
typedef float float4a __attribute__((ext_vector_type(4), aligned(4)));

__device__ __forceinline__ void load_box(const float* __restrict__ p,
                                         float& cx, float& cy,
                                         float& lw, float& ll, float& yaw) {
    float4a a = *reinterpret_cast<const float4a*>(p);      // fields 0,1,2,3
    float4a b = *reinterpret_cast<const float4a*>(p + 3);  // fields 3,4,5,6
    cx = a.x; cy = a.y; lw = a.w; ll = b.y; yaw = b.w;
}

// Green's-theorem closed-form box-clip area (R9/R10). ILP-4: each thread runs
// FOUR independent box pairs; 16 independent loads hoist to the top and stay
// in flight while earlier chains compute -> amortizes the per-block cold-start
// stall (load-wait ~600cyc now covers ~4400cyc of compute, was ~1100).

__device__ __forceinline__ float giou_loss_one(const float* __restrict__ b1,
                                               const float* __restrict__ b2)
{
    float cx1, cy1, lw1, ll1, yaw1;
    float cx2, cy2, lw2, ll2, yaw2;
    load_box(b1, cx1, cy1, lw1, ll1, yaw1);
    load_box(b2, cx2, cy2, lw2, ll2, yaw2);
    float w1 = __expf(lw1), l1 = __expf(ll1);
    float w2 = __expf(lw2), l2 = __expf(ll2);

    float s1 = __sinf(yaw1), c1 = __cosf(yaw1);
    float s2 = __sinf(yaw2), c2 = __cosf(yaw2);
    float hx1 = 0.5f * w1, hy1 = 0.5f * l1;
    float hx  = 0.5f * w2, hy  = 0.5f * l2;   // box2 half-extents (clip box)

    // world-frame enclosing bbox via exact extent identity |u|+|v|
    float e1x = fmaf(hx1, fabsf(c1), hy1 * fabsf(s1));
    float e1y = fmaf(hx1, fabsf(s1), hy1 * fabsf(c1));
    float e2x = fmaf(hx, fabsf(c2), hy * fabsf(s2));
    float e2y = fmaf(hx, fabsf(s2), hy * fabsf(c2));
    float enc;
    {
        float xmin = fminf(cx1 - e1x, cx2 - e2x);
        float xmax = fmaxf(cx1 + e1x, cx2 + e2x);
        float ymin = fminf(cy1 - e1y, cy2 - e2y);
        float ymax = fmaxf(cy1 + e1y, cy2 + e2y);
        enc = (xmax - xmin) * (ymax - ymin);
    }

    // ---- transform quad1 into box2's frame (box2 -> axis-aligned) ----
    float sr = s1 * c2 - c1 * s2;       // sin(yaw1-yaw2)
    float cr = c1 * c2 + s1 * s2;       // cos(yaw1-yaw2)
    float tx = cx1 - cx2, ty = cy1 - cy2;
    float dxc =  c2 * tx + s2 * ty;     // R(-yaw2)*(c1-c2)
    float dyc = -s2 * tx + c2 * ty;
    float ux = hx1 * cr, uy = hx1 * sr;
    float vx = -hy1 * sr, vy = hy1 * cr;

    // CCW corners: d-u-v, d+u-v, d+u+v, d-u+v
    float qx[4], qy[4];
    qx[0] = dxc - ux - vx;  qy[0] = dyc - uy - vy;
    qx[1] = dxc + ux - vx;  qy[1] = dyc + uy - vy;
    qx[2] = dxc + ux + vx;  qy[2] = dyc + uy + vy;
    qx[3] = dxc - ux + vx;  qy[3] = dyc - uy + vy;

    // edge vectors (exact): e0=+2u e1=+2v e2=-2u e3=-2v; 4 shared rcps
    float Ux = 2.0f * ux, Uy = 2.0f * uy;
    float Vx = 2.0f * vx, Vy = 2.0f * vy;
    float rUx = frcp_eps(Ux), rUy = frcp_eps(Uy);
    float rVx = frcp_eps(Vx), rVy = frcp_eps(Vy);

    // hoisted per-vertex threshold compares (shared by adjacent edges)
    bool gT[4], gB[4];
#pragma unroll
    for (int k = 0; k < 4; ++k) { gT[k] = qy[k] > hy; gB[k] = qy[k] > -hy; }

    const float INFP = __int_as_float(0x7f800000);
    float areaP = 0.0f;
    float xTmin = INFP, xTmax = -INFP;   // crossings with y=+hy
    float xBmin = INFP, xBmax = -INFP;   // crossings with y=-hy
#pragma unroll
    for (int i = 0; i < 4; ++i) {
        float px = qx[i], py = qy[i];
        int ip1 = (i + 1) & 3;
        // edge direction and shared reciprocals (negation = input modifier)
        float dxe = (i == 0) ? Ux : (i == 1) ? Vx : (i == 2) ? -Ux : -Vx;
        float dye = (i == 0) ? Uy : (i == 1) ? Vy : (i == 2) ? -Uy : -Vy;
        float rdx = (i == 0) ? rUx : (i == 1) ? rVx : (i == 2) ? -rUx : -rVx;
        float rdy = (i == 0) ? rUy : (i == 1) ? rVy : (i == 2) ? -rUy : -rVy;

        // parameter interval of this edge inside the box
        float ta = (-hx - px) * rdx, tb = (hx - px) * rdx;
        float txlo = fminf(ta, tb), txhi = fmaxf(ta, tb);
        float tc = (-hy - py) * rdy, td = (hy - py) * rdy;
        float tylo = fminf(tc, td), tyhi = fmaxf(tc, td);
        float t0 = fmaxf(fmaxf(txlo, tylo), 0.0f);
        float t1 = fminf(fminf(txhi, tyhi), 1.0f);
        float dt = fmaxf(t1 - t0, 0.0f);
        // -∫ y dx over [t0,t1]
        areaP -= dxe * dt * fmaf(0.5f * dye, t0 + t1, py);

        // crossings with the horizontal box lines (correction terms)
        bool crT = gT[i] != gT[ip1];
        float xT = fmaf(td, dxe, px);            // td == (hy-py)*rdy
        xTmin = fminf(xTmin, crT ? xT : INFP);
        xTmax = fmaxf(xTmax, crT ? xT : -INFP);
        bool crB = gB[i] != gB[ip1];
        float xB = fmaf(tc, dxe, px);            // tc == (-hy-py)*rdy
        xBmin = fminf(xBmin, crB ? xB : INFP);
        xBmax = fmaxf(xBmax, crB ? xB : -INFP);
    }
    // empty-crossing case: -INF - INF = -INF -> max(0,.) = 0 (no guards)
    float Ltop = fmaxf(0.0f, fminf(xTmax, hx) - fmaxf(xTmin, -hx));
    float Lbot = fmaxf(0.0f, fminf(xBmax, hx) - fmaxf(xBmin, -hx));
    float inter = fabsf(fmaf(hy, Ltop + Lbot, areaP));

    // ---- giou (areas rotation-invariant; bbox in world frame) ----
    float area1 = w1 * l1, area2 = w2 * l2;
    float uni = area1 + area2 - inter;
    float giou = inter * frcp(uni + 1e-8f) - (enc - uni) * frcp(enc + 1e-8f);
    return 1.0f - giou;
}

__global__ __launch_bounds__(NTH) void giou_kernel(
    const float* __restrict__ box, const float* __restrict__ tbox,
    double* __restrict__ wsum, int N)
{
    __shared__ double red[4];
    const int tid = threadIdx.x;
    const int base = blockIdx.x * (4 * NTH) + tid;

    // branchless tail: clamp index, select-to-zero -> one straight-line block
    float loss = 0.0f;
#pragma unroll
    for (int k = 0; k < 4; ++k) {
        int g = base + k * NTH;
        int c = g < N ? g : N - 1;
        float lk = giou_loss_one(box + (size_t)c * 7, tbox + (size_t)c * 7);
        loss += (g < N ? lk : 0.0f);
    }

    // ---- reduction: f32 wave shuffle -> f64 block partial -> per-block store ----
#pragma unroll
    for (int o = 32; o > 0; o >>= 1) loss += __shfl_down(loss, o, 64);

    if ((tid & 63) == 0) red[tid >> 6] = (double)loss;
    __syncthreads();
    if (tid == 0)
        wsum[blockIdx.x] = red[0] + red[1] + red[2] + red[3];  // no memset, no atomic
}

__global__ __launch_bounds__(NTH) void finalize_kernel(
    const double* __restrict__ ws, int nblk,
    const int* __restrict__ avgp, float* __restrict__ out)
{
    __shared__ double r[NTH];
    int t = threadIdx.x;
    double v = 0.0;
    for (int i = t; i < nblk; i += NTH) v += ws[i];
    r[t] = v;
    __syncthreads();
#pragma unroll
    for (int s = NTH / 2; s > 0; s >>= 1) {
        if (t < s) r[t] += r[t + s];
        __syncthreads();
    }
    if (t == 0) {
        int ib = *avgp;
        float fb = __int_as_float(ib);
        float av;
        if (ib > 0 && fabsf(fb) < 1e-20f) av = (float)ib;   // int32 payload
        else av = fb;                                        // f32 payload fallback
        if (!(av >= 1.0f)) av = 1.0f;
        out[0] = (float)(r[0] / (double)av);
    }
}

extern "C" void kernel_launch(void* const* d_in, const int* in_sizes, int n_in,
                              void* d_out, int out_size, void* d_ws, size_t ws_size,
                              hipStream_t stream) {
    const float* box  = (const float*)d_in[0];
    const float* tbox = (const float*)d_in[1];
    const int*   avgp = (const int*)d_in[2];
    int N = in_sizes[0] / 7;
    double* ws = (double*)d_ws;

    int blocks = (N + 4 * NTH - 1) / (4 * NTH);
    giou_kernel<<<blocks, NTH, 0, stream>>>(box, tbox, ws, N);
    finalize_kernel<<<1, NTH, 0, stream>>>(ws, blocks, avgp, (float*)d_out);
}